// Round 8
// baseline (618.674 us; speedup 1.0000x reference)
//
#include <hip/hip_runtime.h>
#include <hip/hip_cooperative_groups.h>

namespace cg = cooperative_groups;

#define M 8192
#define N 4096
#define K 4096
#define BM 256
#define BN 256
#define BK 64
#define NKT (K / BK)     // 64 K-tiles
#define NIT (NKT / 2)    // 32 main-loop iterations (2 K-tiles each)

typedef __attribute__((ext_vector_type(8))) short bf16x8;
typedef __attribute__((ext_vector_type(4))) short bf16x4;
typedef __attribute__((ext_vector_type(4))) float f32x4;
typedef __attribute__((address_space(1))) const unsigned GU;
typedef __attribute__((address_space(3))) unsigned LU;

__device__ __forceinline__ unsigned short f2bf(float f) {
    unsigned u = __float_as_uint(f);
    u += 0x7fffu + ((u >> 16) & 1u);   // round-to-nearest-even
    return (unsigned short)(u >> 16);
}

// quantize one value given the rowmax bits (exactly ilogb/ldexp for normal mx>0)
__device__ __forceinline__ float quant1(float v, unsigned mb) {
    const unsigned eb   = mb & 0x7f800000u;
    const float    step = __uint_as_float(eb - 0x03000000u);   // 2^(e-6)
    const float    inv  = __uint_as_float(0x82000000u - eb);   // 2^(6-e)
    const float    qq   = floorf(v * inv + 0.5f) * step;
    return fmaxf(mb ? qq : v, 0.f);
}

// ------- fused fp32->bf16 convert for x and W, 4-deep MLP; also zeroes rowmax -------
__global__ __launch_bounds__(256) void cvt_bf16_2(
    const float* __restrict__ s1, unsigned short* __restrict__ d1, int n1_4,
    const float* __restrict__ s2, unsigned short* __restrict__ d2, int n2_4,
    int* __restrict__ rowmax)
{
    if (blockIdx.x < 32) rowmax[(blockIdx.x << 8) | threadIdx.x] = 0;   // 8192 ints

    const int span = gridDim.x * blockDim.x;
    const int tid  = blockIdx.x * blockDim.x + threadIdx.x;
    const int total = n1_4 + n2_4;

    for (int base = tid; base < total; base += 4 * span) {
        f32x4 v[4];
        #pragma unroll
        for (int j = 0; j < 4; ++j) {
            const int i = base + j * span;
            const f32x4* p = (i < n1_4) ? ((const f32x4*)s1) + i
                                        : ((const f32x4*)s2) + (i - n1_4);
            v[j] = *p;
        }
        #pragma unroll
        for (int j = 0; j < 4; ++j) {
            const int i = base + j * span;
            bf16x4 o;
            #pragma unroll
            for (int k = 0; k < 4; ++k) o[k] = (short)f2bf(v[j][k]);
            bf16x4* q = (i < n1_4) ? ((bf16x4*)d1) + i : ((bf16x4*)d2) + (i - n1_4);
            *q = o;
        }
    }
}

// ---------------- cooperative 256x256 8-phase GEMM + fused quantize ----------------
#define BAR()   __builtin_amdgcn_s_barrier()
#define LGKM0() do { asm volatile("s_waitcnt lgkmcnt(0)" ::: "memory"); \
                     __builtin_amdgcn_sched_barrier(0); } while (0)
#define LGKM8() asm volatile("s_waitcnt lgkmcnt(8)" ::: "memory")
#define VM6()   asm volatile("s_waitcnt vmcnt(6)" ::: "memory")
#define VM0()   asm volatile("s_waitcnt vmcnt(0)" ::: "memory")

#define QUAD(AR, BR, MOFF, NOFF)                                               \
    do {                                                                       \
        __builtin_amdgcn_s_setprio(1);                                         \
        _Pragma("unroll")                                                      \
        for (int m_ = 0; m_ < 4; ++m_) {                                       \
            _Pragma("unroll")                                                  \
            for (int n_ = 0; n_ < 2; ++n_) {                                   \
                acc[MOFF + m_][NOFF + n_] =                                    \
                    __builtin_amdgcn_mfma_f32_16x16x32_bf16(                   \
                        AR[m_][0], BR[n_][0], acc[MOFF + m_][NOFF + n_], 0, 0, 0); \
                acc[MOFF + m_][NOFF + n_] =                                    \
                    __builtin_amdgcn_mfma_f32_16x16x32_bf16(                   \
                        AR[m_][1], BR[n_][1], acc[MOFF + m_][NOFF + n_], 0, 0, 0); \
            }                                                                  \
        }                                                                      \
        __builtin_amdgcn_s_setprio(0);                                         \
    } while (0)

__global__ __launch_bounds__(512, 2) void gemm_fused(
    const unsigned short* __restrict__ xb, const unsigned short* __restrict__ wb,
    const float* __restrict__ bias, float* __restrict__ out,
    int* __restrict__ rowmax)
{
    // 128-KiB LDS pool: main loop A dbuf [0..32767], B dbuf [32768..65535];
    // epilogue reuses it as float[128][256]
    __shared__ __align__(16) short smem[65536];

    const int t    = threadIdx.x;     // 0..511
    const int w_id = t >> 6;
    const int l    = t & 63;
    const int wr   = w_id >> 2;       // 0..1 : A half (128 rows)
    const int wc   = w_id & 3;        // 0..3 : 64-col B slice
    const int lr   = l & 15;
    const int g    = l >> 4;

    const int srow_l = l >> 2;
    const int scol_l = ((l & 3) * 8) ^ ((l >> 5) * 16);   // inverse st_16x32 on source
    const int loff   = lr * 32 + ((g * 8) ^ ((lr >> 3) << 4));

    // block -> 2 tiles: (tm, tn0) and (tm, tn0+8); same A panel
    const int bid = blockIdx.x;       // 0..255
    const int tm  = bid & 31;
    const int bm  = tm * BM;
    const int bn0 = (bid >> 5) * BN;
    const int bn1 = bn0 + 8 * BN;

    f32x4 acc[8][4];

    // ---- K-loop over one tile; leaves result in acc; smem drained at exit ----
    auto run_tile = [&](const unsigned short* gA, const unsigned short* gB) {
        __syncthreads();              // prior smem users done before staging
        #pragma unroll
        for (int m = 0; m < 8; ++m)
            #pragma unroll
            for (int n = 0; n < 4; ++n)
                acc[m][n] = (f32x4){0.f, 0.f, 0.f, 0.f};

        auto stageA = [&](int buf, int h, int kt) {
            #pragma unroll
            for (int j = 0; j < 2; ++j) {
                const int s = w_id * 2 + j;
                const unsigned short* gp =
                    gA + (size_t)(h * 128 + (s >> 1) * 16 + srow_l) * K
                       + kt * 64 + (s & 1) * 32 + scol_l;
                __builtin_amdgcn_global_load_lds(
                    (const GU*)gp, (LU*)&smem[buf * 16384 + h * 8192 + s * 512], 16, 0, 0);
            }
        };
        auto stageB = [&](int buf, int h, int kt) {
            #pragma unroll
            for (int j = 0; j < 2; ++j) {
                const int s = w_id * 2 + j;
                const unsigned short* gp =
                    gB + (size_t)(h * 128 + (s >> 1) * 16 + srow_l) * K
                       + kt * 64 + (s & 1) * 32 + scol_l;
                __builtin_amdgcn_global_load_lds(
                    (const GU*)gp,
                    (LU*)&smem[32768 + buf * 16384 + h * 8192 + s * 512], 16, 0, 0);
            }
        };
        auto ldA = [&](int buf, int m, int ks) -> bf16x8 {
            return *(const bf16x8*)&smem[buf * 16384 + wr * 8192 + (m * 2 + ks) * 512 + loff];
        };
        auto ldB = [&](int buf, int n, int ks) -> bf16x8 {
            return *(const bf16x8*)&smem[32768 + buf * 16384 + (wc >> 1) * 8192 +
                                         (((wc & 1) * 4 + n) * 2 + ks) * 512 + loff];
        };

        bf16x8 a03[4][2], a47[4][2], b01[2][2], b23[2][2];

        // prologue: tile0 (4 half-tiles, buf0) + tile1 (3 half-tiles, buf1)
        stageB(0, 0, 0); stageB(0, 1, 0); stageA(0, 0, 0); stageA(0, 1, 0);
        stageB(1, 0, 1); stageB(1, 1, 1); stageA(1, 0, 1);
        VM6();
        BAR();

        for (int it = 0; it < NIT; ++it) {
            const int t1  = 2 * it + 1;
            const int tp0 = (2 * it + 2) & (NKT - 1);
            const int tp1 = (2 * it + 3) & (NKT - 1);

            // ---- K-tile 2it from buf0 ----
            #pragma unroll
            for (int m = 0; m < 4; ++m) { a03[m][0] = ldA(0, m, 0); a03[m][1] = ldA(0, m, 1); }
            #pragma unroll
            for (int n = 0; n < 2; ++n) { b01[n][0] = ldB(0, n, 0); b01[n][1] = ldB(0, n, 1); }
            stageA(1, 1, t1);
            LGKM8();
            BAR(); LGKM0();
            QUAD(a03, b01, 0, 0);
            BAR();

            #pragma unroll
            for (int n = 0; n < 2; ++n) { b23[n][0] = ldB(0, 2 + n, 0); b23[n][1] = ldB(0, 2 + n, 1); }
            stageB(0, 0, tp0);
            BAR(); LGKM0();
            QUAD(a03, b23, 0, 2);
            BAR();

            #pragma unroll
            for (int m = 0; m < 4; ++m) { a47[m][0] = ldA(0, 4 + m, 0); a47[m][1] = ldA(0, 4 + m, 1); }
            stageB(0, 1, tp0);
            BAR(); LGKM0();
            QUAD(a47, b23, 4, 2);
            BAR();

            stageA(0, 0, tp0);
            BAR(); LGKM0();
            QUAD(a47, b01, 4, 0);
            VM6();
            BAR();

            // ---- K-tile 2it+1 from buf1 ----
            #pragma unroll
            for (int m = 0; m < 4; ++m) { a03[m][0] = ldA(1, m, 0); a03[m][1] = ldA(1, m, 1); }
            #pragma unroll
            for (int n = 0; n < 2; ++n) { b01[n][0] = ldB(1, n, 0); b01[n][1] = ldB(1, n, 1); }
            stageA(0, 1, tp0);
            LGKM8();
            BAR(); LGKM0();
            QUAD(a03, b01, 0, 0);
            BAR();

            #pragma unroll
            for (int n = 0; n < 2; ++n) { b23[n][0] = ldB(1, 2 + n, 0); b23[n][1] = ldB(1, 2 + n, 1); }
            stageB(1, 0, tp1);
            BAR(); LGKM0();
            QUAD(a03, b23, 0, 2);
            BAR();

            #pragma unroll
            for (int m = 0; m < 4; ++m) { a47[m][0] = ldA(1, 4 + m, 0); a47[m][1] = ldA(1, 4 + m, 1); }
            stageB(1, 1, tp1);
            BAR(); LGKM0();
            QUAD(a47, b23, 4, 2);
            BAR();

            stageA(1, 0, tp1);
            BAR(); LGKM0();
            QUAD(a47, b01, 4, 0);
            VM6();
            BAR();
        }

        VM0();                 // drain wrapped prefetches before smem reuse
        __syncthreads();
    };

    // ---- bias fold + per-row |max| -> device-scope atomicMax ----
    auto rowmax_update = [&](int bm_, int bn_) {
        float bv[4];
        #pragma unroll
        for (int n = 0; n < 4; ++n)
            bv[n] = bias[bn_ + wc * 64 + n * 16 + lr];
        #pragma unroll
        for (int m = 0; m < 8; ++m) {
            #pragma unroll
            for (int r = 0; r < 4; ++r) {
                const int row = bm_ + wr * 128 + m * 16 + g * 4 + r;
                float amax = 0.f;
                #pragma unroll
                for (int n = 0; n < 4; ++n) {
                    acc[m][n][r] += bv[n];
                    amax = fmaxf(amax, fabsf(acc[m][n][r]));
                }
                #pragma unroll
                for (int off = 1; off < 16; off <<= 1)
                    amax = fmaxf(amax, __shfl_xor(amax, off));
                if (lr == 0)
                    atomicMax(rowmax + row, __float_as_int(amax));
            }
        }
    };

    // ---- LDS-transposed coalesced fp32 store of acc ----
    auto store_tile = [&](int bm_, int bn_) {
        float* hs = (float*)smem;
        #pragma unroll
        for (int p = 0; p < 2; ++p) {
            if (p) __syncthreads();
            if (wr == p) {
                #pragma unroll
                for (int m = 0; m < 8; ++m)
                    #pragma unroll
                    for (int r = 0; r < 4; ++r)
                        #pragma unroll
                        for (int n = 0; n < 4; ++n)
                            hs[(m * 16 + g * 4 + r) * 256 + wc * 64 + n * 16 + lr] =
                                acc[m][n][r];
            }
            __syncthreads();
            #pragma unroll
            for (int j = 0; j < 16; ++j) {
                const int fi  = j * 2048 + t * 4;
                const int row = fi >> 8;
                const int col = fi & 255;
                *(f32x4*)&out[(size_t)(bm_ + p * 128 + row) * N + bn_ + col] =
                    *(const f32x4*)&hs[fi];
            }
        }
    };

    // ================= phase 1: tile0 -> h stored fp32 =================
    run_tile(xb + (size_t)bm * K, wb + (size_t)bn0 * K);
    rowmax_update(bm, bn0);
    store_tile(bm, bn0);

    // ================= phase 2: tile1 -> acc stays in regs =============
    run_tile(xb + (size_t)bm * K, wb + (size_t)bn1 * K);
    rowmax_update(bm, bn1);

    // ================= grid-wide sync: rowmax complete =================
    __threadfence();
    cg::this_grid().sync();

    // ================= phase 3: quantize tile1 from registers ==========
    #pragma unroll
    for (int m = 0; m < 8; ++m) {
        #pragma unroll
        for (int r = 0; r < 4; ++r) {
            const int row = bm + wr * 128 + m * 16 + g * 4 + r;
            const unsigned mb = (unsigned)__hip_atomic_load(
                rowmax + row, __ATOMIC_RELAXED, __HIP_MEMORY_SCOPE_AGENT);
            #pragma unroll
            for (int n = 0; n < 4; ++n)
                acc[m][n][r] = quant1(acc[m][n][r], mb);
        }
    }
    __syncthreads();             // smem idle since run_tile exit; re-use for transpose
    store_tile(bm, bn1);

    // ================= phase 4: quantize tile0 in place ================
    // 512 threads x f32x4 = 8 rows/iter; wave-uniform row -> scalar rowmax
    #pragma unroll 1
    for (int jb = 0; jb < 32; jb += 4) {
        f32x4 v[4];
        unsigned mb[4];
        int rowv[4];
        #pragma unroll
        for (int jj = 0; jj < 4; ++jj) {
            rowv[jj] = bm + (jb + jj) * 8 + (t >> 6);
            v[jj] = *(const f32x4*)&out[(size_t)rowv[jj] * N + bn0 + (t & 63) * 4];
        }
        #pragma unroll
        for (int jj = 0; jj < 4; ++jj)
            mb[jj] = (unsigned)__hip_atomic_load(
                rowmax + rowv[jj], __ATOMIC_RELAXED, __HIP_MEMORY_SCOPE_AGENT);
        #pragma unroll
        for (int jj = 0; jj < 4; ++jj) {
            f32x4 q;
            #pragma unroll
            for (int k = 0; k < 4; ++k) q[k] = quant1(v[jj][k], mb[jj]);
            *(f32x4*)&out[(size_t)rowv[jj] * N + bn0 + (t & 63) * 4] = q;
        }
    }
}

extern "C" void kernel_launch(void* const* d_in, const int* in_sizes, int n_in,
                              void* d_out, int out_size, void* d_ws, size_t ws_size,
                              hipStream_t stream) {
    const float* x = (const float*)d_in[0];
    const float* w = (const float*)d_in[1];
    const float* b = (const float*)d_in[2];
    float* out = (float*)d_out;

    const size_t XB = (size_t)M * K * 2;   // 64 MiB
    const size_t WB = (size_t)N * K * 2;   // 32 MiB

    unsigned short* xb = (unsigned short*)d_ws;
    unsigned short* wb = (unsigned short*)((char*)d_ws + XB);
    int* rowmax        = (int*)((char*)d_ws + XB + WB);

    cvt_bf16_2<<<3072, 256, 0, stream>>>(x, xb, (M * K) / 4, w, wb, (N * K) / 4, rowmax);

    const unsigned short* xbp = xb;
    const unsigned short* wbp = wb;
    const float* bp = b;
    float* outp = out;
    int* rmp = rowmax;
    void* kargs[] = {(void*)&xbp, (void*)&wbp, (void*)&bp, (void*)&outp, (void*)&rmp};
    hipLaunchCooperativeKernel((void*)gemm_fused, dim3(256), dim3(512),
                               kargs, 0, stream);
}